// Round 1
// baseline (311.668 us; speedup 1.0000x reference)
//
#include <hip/hip_runtime.h>
#include <stdint.h>

typedef __attribute__((ext_vector_type(8))) short short8;
typedef __attribute__((ext_vector_type(4))) float f32x4;
typedef unsigned short ushort_t;

// RNE float -> bf16 bits
__device__ __forceinline__ ushort_t f2bf(float f) {
  union { float f; unsigned u; } v; v.f = f;
  unsigned r = v.u + 0x7fffu + ((v.u >> 16) & 1u);
  return (ushort_t)(r >> 16);
}

#define AS1(p) ((const __attribute__((address_space(1))) void*)(const void*)(p))
#define AS3(p) ((__attribute__((address_space(3))) void*)(void*)(p))

// ---------------- fp32 -> bf16 cast (vectorized, 8 elems/thread) ----------------
__global__ void cvt_bf16(const float* __restrict__ in, ushort_t* __restrict__ out, int n) {
  int i = blockIdx.x * blockDim.x + threadIdx.x;
  int base = i * 8;
  if (base >= n) return;
  float4 f0 = *(const float4*)(in + base);
  float4 f1 = *(const float4*)(in + base + 4);
  short8 r;
  r[0] = (short)f2bf(f0.x); r[1] = (short)f2bf(f0.y);
  r[2] = (short)f2bf(f0.z); r[3] = (short)f2bf(f0.w);
  r[4] = (short)f2bf(f1.x); r[5] = (short)f2bf(f1.y);
  r[6] = (short)f2bf(f1.z); r[7] = (short)f2bf(f1.w);
  *(short8*)(out + base) = r;
}

// ---------------- QKV GEMM: C[m,n] = x[m,:] . W[n,:] + b[n] ----------------
// M=8192, N=3072, K=1024. A=[M][K] bf16, Bw=[N][K] bf16 (both K-contiguous).
// 128x128 tile, BK=32, 4 waves (2x2 of 64x64), double-buffered LDS via global_load_lds.
// Epilogue: +bias, Q scaled by 0.125, write bf16 to qkv[s][b][h][t][d].
__global__ __launch_bounds__(256)
void qkv_gemm(const ushort_t* __restrict__ A, const ushort_t* __restrict__ Bw,
              const float* __restrict__ bias, ushort_t* __restrict__ qkv) {
  __shared__ __align__(16) ushort_t As[2][4096];
  __shared__ __align__(16) ushort_t Bs[2][4096];
  const int tid = threadIdx.x;

  // XCD-aware swizzle: 1536 blocks = 8 * 192 (bijective)
  int bid = blockIdx.x;
  int swz = (bid & 7) * 192 + (bid >> 3);
  const int bm = swz / 24, bn = swz - bm * 24;   // 64 x 24 tiles
  const int row0 = bm << 7, col0 = bn << 7;

  const int lane = tid & 63, a_ = lane & 15, g = lane >> 4, w = tid >> 6;
  const int wm = w >> 1, wn = w & 1;

  f32x4 acc[4][4];
#pragma unroll
  for (int i = 0; i < 4; ++i)
#pragma unroll
    for (int j = 0; j < 4; ++j) acc[i][j] = (f32x4){0.f, 0.f, 0.f, 0.f};

  auto stage = [&](int buf, int k0) {
#pragma unroll
    for (int i = 0; i < 2; ++i) {
      int idx = (i << 8) + tid;          // 16B chunk index, 0..511
      int rr = idx >> 2;                 // tile row 0..127
      int cc = (idx & 3) << 3;           // k offset in elems
      __builtin_amdgcn_global_load_lds(AS1(A + (size_t)(row0 + rr) * 1024 + k0 + cc),
                                       AS3(&As[buf][idx << 3]), 16, 0, 0);
      __builtin_amdgcn_global_load_lds(AS1(Bw + (size_t)(col0 + rr) * 1024 + k0 + cc),
                                       AS3(&Bs[buf][idx << 3]), 16, 0, 0);
    }
  };

  stage(0, 0);
  __syncthreads();
  int buf = 0;
  for (int kt = 0; kt < 32; ++kt) {
    if (kt < 31) stage(buf ^ 1, (kt + 1) << 5);
    short8 af[4], bf[4];
#pragma unroll
    for (int mi = 0; mi < 4; ++mi)
      af[mi] = *(const short8*)&As[buf][((wm << 6) + (mi << 4) + a_) * 32 + (g << 3)];
#pragma unroll
    for (int ni = 0; ni < 4; ++ni)
      bf[ni] = *(const short8*)&Bs[buf][((wn << 6) + (ni << 4) + a_) * 32 + (g << 3)];
#pragma unroll
    for (int mi = 0; mi < 4; ++mi)
#pragma unroll
      for (int ni = 0; ni < 4; ++ni)
        acc[mi][ni] = __builtin_amdgcn_mfma_f32_16x16x32_bf16(af[mi], bf[ni], acc[mi][ni], 0, 0, 0);
    __syncthreads();
    buf ^= 1;
  }

  // epilogue: C/D layout row = g*4+r, col = a_
  float bia[4];
#pragma unroll
  for (int ni = 0; ni < 4; ++ni) bia[ni] = bias[col0 + (wn << 6) + (ni << 4) + a_];
#pragma unroll
  for (int ni = 0; ni < 4; ++ni) {
    int n = col0 + (wn << 6) + (ni << 4) + a_;
    int s_ = n >> 10;                 // 0=Q 1=K 2=V
    int h = (n >> 6) & 15;
    int d = n & 63;
    float sc = (s_ == 0) ? 0.125f : 1.0f;   // fold 1/sqrt(64) into Q
    ushort_t* base = qkv + (size_t)s_ * 8388608 + (size_t)h * 131072 + d;
#pragma unroll
    for (int mi = 0; mi < 4; ++mi) {
#pragma unroll
      for (int r = 0; r < 4; ++r) {
        int mrow = row0 + (wm << 6) + (mi << 4) + (g << 2) + r;
        int b_ = mrow >> 11, t = mrow & 2047;
        float v = (acc[mi][ni][r] + bia[ni]) * sc;
        base[(size_t)b_ * 2097152 + ((size_t)t << 6)] = f2bf(v);
      }
    }
  }
}

// ---------------- flash attention (causal) ----------------
// qkv[s][b][h][t][d] bf16, s stride 8388608, (b,h) stride 131072.
// grid: 64 bh * 32 qblocks(64 rows). 4 waves x 16 q-rows.
__global__ __launch_bounds__(256)
void attn_fwd(const ushort_t* __restrict__ qkv, float* __restrict__ out) {
  __shared__ __align__(16) ushort_t Ks[4096];      // 64x64, XOR-chunk-swizzled
  __shared__ __align__(16) ushort_t Vts[64 * 72];  // [d][k] transposed, padded
  __shared__ __align__(16) ushort_t Ps[4 * 16 * 72]; // per-wave P tile, padded
  const int tid = threadIdx.x;
  const int lane = tid & 63, a_ = lane & 15, g = lane >> 4, w = tid >> 6;
  const int bh = blockIdx.x >> 5, qb = blockIdx.x & 31;
  const int q0 = qb << 6;
  const ushort_t* gQ = qkv + (size_t)bh * 131072;
  const ushort_t* gK = gQ + 8388608;
  const ushort_t* gV = gQ + 16777216;

  // Q fragments in registers for the whole KV loop (A-layout: row=a_, k contiguous)
  short8 qf[2];
#pragma unroll
  for (int ss = 0; ss < 2; ++ss)
    qf[ss] = *(const short8*)&gQ[(size_t)(q0 + (w << 4) + a_) * 64 + (ss << 5) + (g << 3)];

  f32x4 o[4];
#pragma unroll
  for (int dt = 0; dt < 4; ++dt) o[dt] = (f32x4){0.f, 0.f, 0.f, 0.f};
  float m_[4], l_[4];
#pragma unroll
  for (int r = 0; r < 4; ++r) { m_[r] = -__builtin_huge_valf(); l_[r] = 0.f; }

  const int ntiles = (q0 >> 6) + 1;
  const int vrow = tid & 63, vd0 = (tid >> 6) << 3;

  for (int tkv = 0; tkv < ntiles; ++tkv) {
    const int k0 = tkv << 6;
    // K tile: global_load_lds linear dest + inverse-swizzled global source.
    // logical layout [row][64], chunk c (16B) stored at c ^ (row&7).
#pragma unroll
    for (int i = 0; i < 2; ++i) {
      int idx = (i << 8) + tid;
      int rr = idx >> 3, pc = idx & 7, lc = pc ^ (rr & 7);
      __builtin_amdgcn_global_load_lds(AS1(gK + (size_t)(k0 + rr) * 64 + (lc << 3)),
                                       AS3(&Ks[idx << 3]), 16, 0, 0);
    }
    // V tile: register-staged transpose into Vts[d][k] (stride 72)
    {
      short8 v0 = *(const short8*)&gV[(size_t)(k0 + vrow) * 64 + vd0];
      short8 v1 = *(const short8*)&gV[(size_t)(k0 + vrow) * 64 + vd0 + 32];
#pragma unroll
      for (int j = 0; j < 8; ++j) {
        Vts[(vd0 + j) * 72 + vrow] = (ushort_t)v0[j];
        Vts[(vd0 + 32 + j) * 72 + vrow] = (ushort_t)v1[j];
      }
    }
    __syncthreads();

    // S = Q K^T  (C-layout: row q = g*4+r, col k = a_)
    f32x4 s[4];
#pragma unroll
    for (int kt = 0; kt < 4; ++kt) {
      s[kt] = (f32x4){0.f, 0.f, 0.f, 0.f};
#pragma unroll
      for (int ss = 0; ss < 2; ++ss) {
        int krow = (kt << 4) + a_;
        int pc = ((ss << 2) + g) ^ (krow & 7);
        short8 kf = *(const short8*)&Ks[krow * 64 + (pc << 3)];
        s[kt] = __builtin_amdgcn_mfma_f32_16x16x32_bf16(qf[ss], kf, s[kt], 0, 0, 0);
      }
    }
    // causal mask on the diagonal tile only
    if (tkv == ntiles - 1) {
#pragma unroll
      for (int kt = 0; kt < 4; ++kt)
#pragma unroll
        for (int r = 0; r < 4; ++r)
          if ((kt << 4) + a_ > (w << 4) + (g << 2) + r) s[kt][r] = -__builtin_huge_valf();
    }

    // online softmax (row-reduce across a_ lanes via shfl_xor 1,2,4,8)
    ushort_t* myP = &Ps[(w << 4) * 72];
#pragma unroll
    for (int r = 0; r < 4; ++r) {
      float tm = fmaxf(fmaxf(s[0][r], s[1][r]), fmaxf(s[2][r], s[3][r]));
      tm = fmaxf(tm, __shfl_xor(tm, 1));
      tm = fmaxf(tm, __shfl_xor(tm, 2));
      tm = fmaxf(tm, __shfl_xor(tm, 4));
      tm = fmaxf(tm, __shfl_xor(tm, 8));
      float mn = fmaxf(m_[r], tm);
      float al = __expf(m_[r] - mn);
      m_[r] = mn;
      float rs = 0.f;
#pragma unroll
      for (int kt = 0; kt < 4; ++kt) {
        float p = __expf(s[kt][r] - mn);
        s[kt][r] = p;
        rs += p;
      }
      rs += __shfl_xor(rs, 1); rs += __shfl_xor(rs, 2);
      rs += __shfl_xor(rs, 4); rs += __shfl_xor(rs, 8);
      l_[r] = l_[r] * al + rs;
#pragma unroll
      for (int dt = 0; dt < 4; ++dt) o[dt][r] *= al;
#pragma unroll
      for (int kt = 0; kt < 4; ++kt)
        myP[((g << 2) + r) * 72 + (kt << 4) + a_] = f2bf(s[kt][r]);
    }

    // P (A-layout) from own-wave LDS; PV with B-frag from Vts[d][k]
    short8 pa0 = *(const short8*)&myP[a_ * 72 + (g << 3)];
    short8 pa1 = *(const short8*)&myP[a_ * 72 + 32 + (g << 3)];
#pragma unroll
    for (int dt = 0; dt < 4; ++dt) {
      short8 vf0 = *(const short8*)&Vts[((dt << 4) + a_) * 72 + (g << 3)];
      short8 vf1 = *(const short8*)&Vts[((dt << 4) + a_) * 72 + 32 + (g << 3)];
      o[dt] = __builtin_amdgcn_mfma_f32_16x16x32_bf16(pa0, vf0, o[dt], 0, 0, 0);
      o[dt] = __builtin_amdgcn_mfma_f32_16x16x32_bf16(pa1, vf1, o[dt], 0, 0, 0);
    }
    __syncthreads();
  }

  // epilogue: out[b][q][h*64+d], fp32
  const int b_ = bh >> 4, h = bh & 15;
#pragma unroll
  for (int r = 0; r < 4; ++r) {
    float inv = 1.f / l_[r];
    int q = q0 + (w << 4) + (g << 2) + r;
    float* orow = out + ((size_t)((b_ << 11) + q) << 10) + (h << 6);
#pragma unroll
    for (int dt = 0; dt < 4; ++dt)
      orow[(dt << 4) + a_] = o[dt][r] * inv;
  }
}

extern "C" void kernel_launch(void* const* d_in, const int* in_sizes, int n_in,
                              void* d_out, int out_size, void* d_ws, size_t ws_size,
                              hipStream_t stream) {
  const float* x = (const float*)d_in[0];   // [4,2048,1024]
  const float* W = (const float*)d_in[1];   // [3072,1024]
  const float* b = (const float*)d_in[2];   // [3072]
  float* out = (float*)d_out;               // [4,2048,1024]

  ushort_t* qkv = (ushort_t*)d_ws;                      // 3*8388608 bf16
  ushort_t* xb  = qkv + (size_t)3 * 8388608;            // 8388608 bf16
  ushort_t* Wb  = xb + 8388608;                         // 3145728 bf16

  hipLaunchKernelGGL(cvt_bf16, dim3(4096), dim3(256), 0, stream, x, xb, 8388608);
  hipLaunchKernelGGL(cvt_bf16, dim3(1536), dim3(256), 0, stream, W, Wb, 3145728);
  hipLaunchKernelGGL(qkv_gemm, dim3(1536), dim3(256), 0, stream, xb, Wb, b, qkv);
  hipLaunchKernelGGL(attn_fwd, dim3(2048), dim3(256), 0, stream, qkv, out);
}

// Round 3
// 176.012 us; speedup vs baseline: 1.7707x; 1.7707x over previous
//
#include <hip/hip_runtime.h>
#include <hip/hip_bf16.h>
#include <stdint.h>

typedef __attribute__((ext_vector_type(8))) short short8;
typedef __attribute__((ext_vector_type(4))) float f32x4;
typedef unsigned short ushort_t;

// RNE float -> bf16 bits
__device__ __forceinline__ ushort_t f2bf(float f) {
  union { float f; unsigned u; } v; v.f = f;
  unsigned r = v.u + 0x7fffu + ((v.u >> 16) & 1u);
  return (ushort_t)(r >> 16);
}

__device__ __forceinline__ unsigned pk_bf16(float lo, float hi) {
  __hip_bfloat162 h = __float22bfloat162_rn(make_float2(lo, hi));
  union { __hip_bfloat162 h; unsigned u; } c; c.h = h;
  return c.u;
}

// 2^x via v_exp_f32 (avoids __exp2f/math.h macro clash in this harness)
__device__ __forceinline__ float exp2_fast(float x) {
  return __builtin_amdgcn_exp2f(x);
}

#define AS1(p) ((const __attribute__((address_space(1))) void*)(const void*)(p))
#define AS3(p) ((__attribute__((address_space(3))) void*)(void*)(p))

// ---------------- fp32 -> bf16 cast ----------------
__global__ void cvt_bf16(const float* __restrict__ in, ushort_t* __restrict__ out, int n) {
  int i = blockIdx.x * blockDim.x + threadIdx.x;
  int base = i * 8;
  if (base >= n) return;
  float4 f0 = *(const float4*)(in + base);
  float4 f1 = *(const float4*)(in + base + 4);
  short8 r;
  r[0] = (short)f2bf(f0.x); r[1] = (short)f2bf(f0.y);
  r[2] = (short)f2bf(f0.z); r[3] = (short)f2bf(f0.w);
  r[4] = (short)f2bf(f1.x); r[5] = (short)f2bf(f1.y);
  r[6] = (short)f2bf(f1.z); r[7] = (short)f2bf(f1.w);
  *(short8*)(out + base) = r;
}

// ---------------- QKV GEMM: C[m,n] = x[m,:] . W[n,:] + b[n] ----------------
__global__ __launch_bounds__(256)
void qkv_gemm(const ushort_t* __restrict__ A, const ushort_t* __restrict__ Bw,
              const float* __restrict__ bias, ushort_t* __restrict__ qkv) {
  __shared__ __align__(16) ushort_t As[2][4096];
  __shared__ __align__(16) ushort_t Bs[2][4096];
  const int tid = threadIdx.x;

  int bid = blockIdx.x;
  int swz = (bid & 7) * 192 + (bid >> 3);
  const int bm = swz / 24, bn = swz - bm * 24;
  const int row0 = bm << 7, col0 = bn << 7;

  const int lane = tid & 63, a_ = lane & 15, g = lane >> 4, w = tid >> 6;
  const int wm = w >> 1, wn = w & 1;

  f32x4 acc[4][4];
#pragma unroll
  for (int i = 0; i < 4; ++i)
#pragma unroll
    for (int j = 0; j < 4; ++j) acc[i][j] = (f32x4){0.f, 0.f, 0.f, 0.f};

  auto stage = [&](int buf, int k0) {
#pragma unroll
    for (int i = 0; i < 2; ++i) {
      int idx = (i << 8) + tid;
      int rr = idx >> 2;
      int cc = (idx & 3) << 3;
      __builtin_amdgcn_global_load_lds(AS1(A + (size_t)(row0 + rr) * 1024 + k0 + cc),
                                       AS3(&As[buf][idx << 3]), 16, 0, 0);
      __builtin_amdgcn_global_load_lds(AS1(Bw + (size_t)(col0 + rr) * 1024 + k0 + cc),
                                       AS3(&Bs[buf][idx << 3]), 16, 0, 0);
    }
  };

  stage(0, 0);
  __syncthreads();
  int buf = 0;
  for (int kt = 0; kt < 32; ++kt) {
    if (kt < 31) stage(buf ^ 1, (kt + 1) << 5);
    short8 af[4], bf[4];
#pragma unroll
    for (int mi = 0; mi < 4; ++mi)
      af[mi] = *(const short8*)&As[buf][((wm << 6) + (mi << 4) + a_) * 32 + (g << 3)];
#pragma unroll
    for (int ni = 0; ni < 4; ++ni)
      bf[ni] = *(const short8*)&Bs[buf][((wn << 6) + (ni << 4) + a_) * 32 + (g << 3)];
#pragma unroll
    for (int mi = 0; mi < 4; ++mi)
#pragma unroll
      for (int ni = 0; ni < 4; ++ni)
        acc[mi][ni] = __builtin_amdgcn_mfma_f32_16x16x32_bf16(af[mi], bf[ni], acc[mi][ni], 0, 0, 0);
    __syncthreads();
    buf ^= 1;
  }

  float bia[4];
#pragma unroll
  for (int ni = 0; ni < 4; ++ni) bia[ni] = bias[col0 + (wn << 6) + (ni << 4) + a_];
#pragma unroll
  for (int ni = 0; ni < 4; ++ni) {
    int n = col0 + (wn << 6) + (ni << 4) + a_;
    int s_ = n >> 10;
    int h = (n >> 6) & 15;
    int d = n & 63;
    // Q carries 1/sqrt(64) * log2(e) so softmax can use exp2 directly
    float sc = (s_ == 0) ? 0.18033688011112042f : 1.0f;
    ushort_t* base = qkv + (size_t)s_ * 8388608 + (size_t)h * 131072 + d;
#pragma unroll
    for (int mi = 0; mi < 4; ++mi) {
#pragma unroll
      for (int r = 0; r < 4; ++r) {
        int mrow = row0 + (wm << 6) + (mi << 4) + (g << 2) + r;
        int b_ = mrow >> 11, t = mrow & 2047;
        float v = (acc[mi][ni][r] + bia[ni]) * sc;
        base[(size_t)b_ * 2097152 + ((size_t)t << 6)] = f2bf(v);
      }
    }
  }
}

// ---------------- flash attention v2 (swapped operands, balanced grid) ----------------
// grid: 64 bh * 16 pairs; block handles q-blocks {pr, 31-pr} (33 tiles each).
// Sᵀ = mfma(K,Q): lane owns q-row (lane&15); Oᵀ = mfma(Vt,P): rescale lane-local.
__global__ __launch_bounds__(256, 4)
void attn_fwd(const ushort_t* __restrict__ qkv, float* __restrict__ out) {
  __shared__ __align__(16) ushort_t Ks[2][4096];   // [64][64] XOR-chunk-swizzled, dbuf
  __shared__ __align__(16) ushort_t Vts[64 * 72];  // [d][k] transposed, pad 8
  __shared__ __align__(16) ushort_t Ps[4][16 * 72];// per-wave P rows (q-major, k contig)
  const int tid = threadIdx.x;
  const int lane = tid & 63, a_ = lane & 15, g = lane >> 4, w = tid >> 6;
  const int bh = blockIdx.x >> 4, pr = blockIdx.x & 15;
  const ushort_t* gQ = qkv + (size_t)bh * 131072;
  const ushort_t* gK = gQ + 8388608;
  const ushort_t* gV = gQ + 16777216;
  const int k2 = (tid & 31) << 1, d0 = (tid >> 5) << 3;  // V transpose assignment
  ushort_t* myP = Ps[w];

  auto stageK = [&](int k0, int buf) {
#pragma unroll
    for (int i = 0; i < 2; ++i) {
      int idx = (i << 8) + tid;
      int rr = idx >> 3, pc = idx & 7, lc = pc ^ (rr & 7);
      __builtin_amdgcn_global_load_lds(AS1(gK + (size_t)(k0 + rr) * 64 + (lc << 3)),
                                       AS3(&Ks[buf][idx << 3]), 16, 0, 0);
    }
  };

  for (int pass = 0; pass < 2; ++pass) {
    const int qb = pass ? (31 - pr) : pr;
    const int nt = qb + 1;
    const int qq0 = qb << 6;

    // Q fragments in registers (rows q = w*16 + a_, k-contig)
    short8 qf0 = *(const short8*)&gQ[(size_t)(qq0 + (w << 4) + a_) * 64 + (g << 3)];
    short8 qf1 = *(const short8*)&gQ[(size_t)(qq0 + (w << 4) + a_) * 64 + 32 + (g << 3)];

    f32x4 o[4];
#pragma unroll
    for (int dt = 0; dt < 4; ++dt) o[dt] = (f32x4){0.f, 0.f, 0.f, 0.f};
    float m_ = -__builtin_huge_valf(), l_ = 0.f;

    __syncthreads();  // previous pass done reading Ks/Vts before restaging
    stageK(0, 0);
    short8 v0r = *(const short8*)&gV[(size_t)k2 * 64 + d0];
    short8 v1r = *(const short8*)&gV[(size_t)(k2 + 1) * 64 + d0];

    for (int t = 0; t < nt; ++t) {
      __syncthreads();  // (A): K(t)/V(t) loads drained; prev-tile Vt readers done
      // commit V(t) transpose: Vt[d][k], paired k in one dword (2-way banks = free)
#pragma unroll
      for (int j = 0; j < 8; ++j) {
        unsigned wd = (unsigned)(ushort_t)v0r[j] | ((unsigned)(ushort_t)v1r[j] << 16);
        *(unsigned*)&Vts[(d0 + j) * 72 + k2] = wd;
      }
      if (t + 1 < nt) {  // prefetch next tile during compute
        stageK((t + 1) << 6, (t + 1) & 1);
        v0r = *(const short8*)&gV[(size_t)((t + 1) * 64 + k2) * 64 + d0];
        v1r = *(const short8*)&gV[(size_t)((t + 1) * 64 + k2 + 1) * 64 + d0];
      }
      __syncthreads();  // (B): Vt visible

      // S^T = K Q^T : C[k-local][q=a_]; lane (a_,g) reg r holds k = kt*16+4g+r
      f32x4 s4[4];
#pragma unroll
      for (int kt = 0; kt < 4; ++kt) {
        s4[kt] = (f32x4){0.f, 0.f, 0.f, 0.f};
        int krow = (kt << 4) + a_;
        const ushort_t* kr = &Ks[t & 1][krow << 6];
#pragma unroll
        for (int ss = 0; ss < 2; ++ss) {
          int pc = ((ss << 2) + g) ^ (krow & 7);
          short8 kf = *(const short8*)&kr[pc << 3];
          s4[kt] = __builtin_amdgcn_mfma_f32_16x16x32_bf16(kf, ss ? qf1 : qf0, s4[kt], 0, 0, 0);
        }
      }
      if (t == nt - 1) {  // causal mask, diagonal tile only
        int qrow = (w << 4) + a_;
#pragma unroll
        for (int kt = 0; kt < 4; ++kt)
#pragma unroll
          for (int r = 0; r < 4; ++r)
            if ((kt << 4) + (g << 2) + r > qrow) s4[kt][r] = -__builtin_huge_valf();
      }

      // online softmax: q-row is lane-local; cross-lane only over g (xor 16,32)
      float tm = s4[0][0];
#pragma unroll
      for (int kt = 0; kt < 4; ++kt)
#pragma unroll
        for (int r = 0; r < 4; ++r) tm = fmaxf(tm, s4[kt][r]);
      tm = fmaxf(tm, __shfl_xor(tm, 16));
      tm = fmaxf(tm, __shfl_xor(tm, 32));
      float mn = fmaxf(m_, tm);
      float al = exp2_fast(m_ - mn);
      m_ = mn;
      float rs = 0.f;
#pragma unroll
      for (int kt = 0; kt < 4; ++kt)
#pragma unroll
        for (int r = 0; r < 4; ++r) {
          float p = exp2_fast(s4[kt][r] - mn);
          s4[kt][r] = p;
          rs += p;
        }
      rs += __shfl_xor(rs, 16);
      rs += __shfl_xor(rs, 32);
      l_ = l_ * al + rs;
#pragma unroll
      for (int dt = 0; dt < 4; ++dt)
#pragma unroll
        for (int r = 0; r < 4; ++r) o[dt][r] *= al;

      // P -> per-wave LDS rows (q = a_, k contiguous), packed bf16 pairs
#pragma unroll
      for (int kt = 0; kt < 4; ++kt) {
        uint2 wp;
        wp.x = pk_bf16(s4[kt][0], s4[kt][1]);
        wp.y = pk_bf16(s4[kt][2], s4[kt][3]);
        *(uint2*)&myP[a_ * 72 + (kt << 4) + (g << 2)] = wp;
      }

      // O^T += V^T P^T : A = Vt rows (d), B = P rows (q); C[d-local][q=a_]
      short8 pf0 = *(const short8*)&myP[a_ * 72 + (g << 3)];
      short8 pf1 = *(const short8*)&myP[a_ * 72 + 32 + (g << 3)];
#pragma unroll
      for (int dt = 0; dt < 4; ++dt) {
        const ushort_t* vr = &Vts[((dt << 4) + a_) * 72];
        short8 va = *(const short8*)&vr[g << 3];
        short8 vb = *(const short8*)&vr[32 + (g << 3)];
        o[dt] = __builtin_amdgcn_mfma_f32_16x16x32_bf16(va, pf0, o[dt], 0, 0, 0);
        o[dt] = __builtin_amdgcn_mfma_f32_16x16x32_bf16(vb, pf1, o[dt], 0, 0, 0);
      }
    }

    // epilogue: lane owns q = a_-row; d = dt*16 + 4g + r contiguous -> float4
    const int b_ = bh >> 4, h = bh & 15;
    const int q = qq0 + (w << 4) + a_;
    float inv = 1.f / l_;
    float* orow = out + ((size_t)(b_ << 11) + q) * 1024 + (h << 6);
#pragma unroll
    for (int dt = 0; dt < 4; ++dt) {
      float4 st;
      st.x = o[dt][0] * inv; st.y = o[dt][1] * inv;
      st.z = o[dt][2] * inv; st.w = o[dt][3] * inv;
      *(float4*)&orow[(dt << 4) + (g << 2)] = st;
    }
  }
}

extern "C" void kernel_launch(void* const* d_in, const int* in_sizes, int n_in,
                              void* d_out, int out_size, void* d_ws, size_t ws_size,
                              hipStream_t stream) {
  const float* x = (const float*)d_in[0];
  const float* W = (const float*)d_in[1];
  const float* b = (const float*)d_in[2];
  float* out = (float*)d_out;

  ushort_t* qkv = (ushort_t*)d_ws;
  ushort_t* xb  = qkv + (size_t)3 * 8388608;
  ushort_t* Wb  = xb + 8388608;

  hipLaunchKernelGGL(cvt_bf16, dim3(4096), dim3(256), 0, stream, x, xb, 8388608);
  hipLaunchKernelGGL(cvt_bf16, dim3(1536), dim3(256), 0, stream, W, Wb, 3145728);
  hipLaunchKernelGGL(qkv_gemm, dim3(1536), dim3(256), 0, stream, xb, Wb, b, qkv);
  hipLaunchKernelGGL(attn_fwd, dim3(1024), dim3(256), 0, stream, qkv, out);
}

// Round 4
// 164.397 us; speedup vs baseline: 1.8958x; 1.0707x over previous
//
#include <hip/hip_runtime.h>
#include <hip/hip_bf16.h>
#include <stdint.h>

typedef __attribute__((ext_vector_type(8))) short short8;
typedef __attribute__((ext_vector_type(4))) float f32x4;
typedef unsigned short ushort_t;

// RNE float -> bf16 bits
__device__ __forceinline__ ushort_t f2bf(float f) {
  union { float f; unsigned u; } v; v.f = f;
  unsigned r = v.u + 0x7fffu + ((v.u >> 16) & 1u);
  return (ushort_t)(r >> 16);
}

__device__ __forceinline__ unsigned pk_bf16(float lo, float hi) {
  __hip_bfloat162 h = __float22bfloat162_rn(make_float2(lo, hi));
  union { __hip_bfloat162 h; unsigned u; } c; c.h = h;
  return c.u;
}

// 2^x via v_exp_f32 (avoids __exp2f/math.h macro clash in this harness)
__device__ __forceinline__ float exp2_fast(float x) {
  return __builtin_amdgcn_exp2f(x);
}

#define AS1(p) ((const __attribute__((address_space(1))) void*)(const void*)(p))
#define AS3(p) ((__attribute__((address_space(3))) void*)(void*)(p))

// ---------------- fp32 -> bf16 cast ----------------
__global__ void cvt_bf16(const float* __restrict__ in, ushort_t* __restrict__ out, int n) {
  int i = blockIdx.x * blockDim.x + threadIdx.x;
  int base = i * 8;
  if (base >= n) return;
  float4 f0 = *(const float4*)(in + base);
  float4 f1 = *(const float4*)(in + base + 4);
  short8 r;
  r[0] = (short)f2bf(f0.x); r[1] = (short)f2bf(f0.y);
  r[2] = (short)f2bf(f0.z); r[3] = (short)f2bf(f0.w);
  r[4] = (short)f2bf(f1.x); r[5] = (short)f2bf(f1.y);
  r[6] = (short)f2bf(f1.z); r[7] = (short)f2bf(f1.w);
  *(short8*)(out + base) = r;
}

// ---------------- QKV GEMM: C[m,n] = x[m,:] . W[n,:] + b[n] ----------------
__global__ __launch_bounds__(256)
void qkv_gemm(const ushort_t* __restrict__ A, const ushort_t* __restrict__ Bw,
              const float* __restrict__ bias, ushort_t* __restrict__ qkv) {
  __shared__ __align__(16) ushort_t As[2][4096];
  __shared__ __align__(16) ushort_t Bs[2][4096];
  const int tid = threadIdx.x;

  int bid = blockIdx.x;
  int swz = (bid & 7) * 192 + (bid >> 3);
  const int bm = swz / 24, bn = swz - bm * 24;
  const int row0 = bm << 7, col0 = bn << 7;

  const int lane = tid & 63, a_ = lane & 15, g = lane >> 4, w = tid >> 6;
  const int wm = w >> 1, wn = w & 1;

  f32x4 acc[4][4];
#pragma unroll
  for (int i = 0; i < 4; ++i)
#pragma unroll
    for (int j = 0; j < 4; ++j) acc[i][j] = (f32x4){0.f, 0.f, 0.f, 0.f};

  auto stage = [&](int buf, int k0) {
#pragma unroll
    for (int i = 0; i < 2; ++i) {
      int idx = (i << 8) + tid;
      int rr = idx >> 2;
      int cc = (idx & 3) << 3;
      __builtin_amdgcn_global_load_lds(AS1(A + (size_t)(row0 + rr) * 1024 + k0 + cc),
                                       AS3(&As[buf][idx << 3]), 16, 0, 0);
      __builtin_amdgcn_global_load_lds(AS1(Bw + (size_t)(col0 + rr) * 1024 + k0 + cc),
                                       AS3(&Bs[buf][idx << 3]), 16, 0, 0);
    }
  };

  stage(0, 0);
  __syncthreads();
  int buf = 0;
  for (int kt = 0; kt < 32; ++kt) {
    if (kt < 31) stage(buf ^ 1, (kt + 1) << 5);
    short8 af[4], bf[4];
#pragma unroll
    for (int mi = 0; mi < 4; ++mi)
      af[mi] = *(const short8*)&As[buf][((wm << 6) + (mi << 4) + a_) * 32 + (g << 3)];
#pragma unroll
    for (int ni = 0; ni < 4; ++ni)
      bf[ni] = *(const short8*)&Bs[buf][((wn << 6) + (ni << 4) + a_) * 32 + (g << 3)];
#pragma unroll
    for (int mi = 0; mi < 4; ++mi)
#pragma unroll
      for (int ni = 0; ni < 4; ++ni)
        acc[mi][ni] = __builtin_amdgcn_mfma_f32_16x16x32_bf16(af[mi], bf[ni], acc[mi][ni], 0, 0, 0);
    __syncthreads();
    buf ^= 1;
  }

  float bia[4];
#pragma unroll
  for (int ni = 0; ni < 4; ++ni) bia[ni] = bias[col0 + (wn << 6) + (ni << 4) + a_];
#pragma unroll
  for (int ni = 0; ni < 4; ++ni) {
    int n = col0 + (wn << 6) + (ni << 4) + a_;
    int s_ = n >> 10;
    int h = (n >> 6) & 15;
    int d = n & 63;
    // Q carries 1/sqrt(64) * log2(e) so softmax can use exp2 directly
    float sc = (s_ == 0) ? 0.18033688011112042f : 1.0f;
    ushort_t* base = qkv + (size_t)s_ * 8388608 + (size_t)h * 131072 + d;
#pragma unroll
    for (int mi = 0; mi < 4; ++mi) {
#pragma unroll
      for (int r = 0; r < 4; ++r) {
        int mrow = row0 + (wm << 6) + (mi << 4) + (g << 2) + r;
        int b_ = mrow >> 11, t = mrow & 2047;
        float v = (acc[mi][ni][r] + bia[ni]) * sc;
        base[(size_t)b_ * 2097152 + ((size_t)t << 6)] = f2bf(v);
      }
    }
  }
}

// ---------------- flash attention v3 ----------------
// 512 blocks x 512 threads. Block = (bh, pr); XCD-affine: bid%8 == bh%8 so all
// q-blocks of a bh share one XCD's L2 (4MB holds its 8 bh x 512KB K/V).
// Two passes: qb = pr, then 15-pr (128-row q-blocks) -> 34 KV tiles per block.
// 8 waves x 16 q-rows; waves 0-3 = rows 0-63, waves 4-7 = rows 64-127.
// S^T = mfma(K,Q): lane owns q-row (lane&15); O^T = mfma(Vt,P): rescale lane-local.
__global__ __launch_bounds__(512, 4)
void attn_fwd(const ushort_t* __restrict__ qkv, float* __restrict__ out) {
  __shared__ __align__(16) ushort_t Ks[2][4096];   // [64][64] XOR-chunk-swizzled, dbuf
  __shared__ __align__(16) ushort_t Vts[64 * 72];  // [d][k] transposed, pad 8
  __shared__ __align__(16) ushort_t Ps[8][16 * 72];// per-wave P rows (q-major, k contig)
  const int tid = threadIdx.x;
  const int lane = tid & 63, a_ = lane & 15, g = lane >> 4, w = tid >> 6;
  // XCD-affine decode
  const int xcd = blockIdx.x & 7, slot = blockIdx.x >> 3;
  const int bh = ((slot >> 3) << 3) | xcd;   // 0..63
  const int pr = slot & 7;                   // 0..7
  const ushort_t* gQ = qkv + (size_t)bh * 131072;
  const ushort_t* gK = gQ + 8388608;
  const ushort_t* gV = gQ + 16777216;
  const int kk = lane;            // V transpose: k row
  const int d0v = w << 3;         // V transpose: d block (8 waves x 8 = 64)
  ushort_t* myP = Ps[w];

  auto stageK = [&](int k0, int buf) {
    int rr = tid >> 3, pc = tid & 7, lc = pc ^ (rr & 7);
    __builtin_amdgcn_global_load_lds(AS1(gK + (size_t)(k0 + rr) * 64 + (lc << 3)),
                                     AS3(&Ks[buf][tid << 3]), 16, 0, 0);
  };

  for (int pass = 0; pass < 2; ++pass) {
    const int qb = pass ? (15 - pr) : pr;     // 128-row q-block index
    const int ntmax = (qb << 1) + 2;
    const int ntw = (qb << 1) + 1 + (w >> 2); // this wave's causal tile count
    const int qq0 = qb << 7;

    // Q fragments in registers (rows q = qq0 + w*16 + a_, k-contig)
    short8 qf0 = *(const short8*)&gQ[(size_t)(qq0 + (w << 4) + a_) * 64 + (g << 3)];
    short8 qf1 = *(const short8*)&gQ[(size_t)(qq0 + (w << 4) + a_) * 64 + 32 + (g << 3)];

    f32x4 o[4];
#pragma unroll
    for (int dt = 0; dt < 4; ++dt) o[dt] = (f32x4){0.f, 0.f, 0.f, 0.f};
    float m_ = -__builtin_huge_valf(), l_ = 0.f;

    __syncthreads();  // previous pass done reading Ks/Vts before restaging
    stageK(0, 0);
    short8 v0r = *(const short8*)&gV[(size_t)kk * 64 + d0v];

    for (int t = 0; t < ntmax; ++t) {
      __syncthreads();  // (A): K(t)/V(t) loads drained; prev-tile Vt readers done
      // commit V(t) transpose: Vt[d][k] (b16 writes, 2 lanes/dword = free)
#pragma unroll
      for (int j = 0; j < 8; ++j)
        Vts[(d0v + j) * 72 + kk] = (ushort_t)v0r[j];
      if (t + 1 < ntmax) {  // prefetch next tile during compute
        stageK((t + 1) << 6, (t + 1) & 1);
        v0r = *(const short8*)&gV[(size_t)((t + 1) * 64 + kk) * 64 + d0v];
      }
      __syncthreads();  // (B): Vt visible

      if (t < ntw) {
        // S^T = K Q^T : C[k-local][q=a_]; lane (a_,g) reg r holds k = kt*16+4g+r
        f32x4 s4[4];
        __builtin_amdgcn_s_setprio(1);
#pragma unroll
        for (int kt = 0; kt < 4; ++kt) {
          s4[kt] = (f32x4){0.f, 0.f, 0.f, 0.f};
          int krow = (kt << 4) + a_;
          const ushort_t* kr = &Ks[t & 1][krow << 6];
#pragma unroll
          for (int ss = 0; ss < 2; ++ss) {
            int pc = ((ss << 2) + g) ^ (krow & 7);
            short8 kf = *(const short8*)&kr[pc << 3];
            s4[kt] = __builtin_amdgcn_mfma_f32_16x16x32_bf16(kf, ss ? qf1 : qf0, s4[kt], 0, 0, 0);
          }
        }
        __builtin_amdgcn_s_setprio(0);
        if (t == ntw - 1) {  // causal mask, diagonal tile only
          int qrow = ((w & 3) << 4) + a_;
#pragma unroll
          for (int kt = 0; kt < 4; ++kt)
#pragma unroll
            for (int r = 0; r < 4; ++r)
              if ((kt << 4) + (g << 2) + r > qrow) s4[kt][r] = -__builtin_huge_valf();
        }

        // online softmax: q-row lane-local; cross-lane only over g (xor 16,32)
        float tm = s4[0][0];
#pragma unroll
        for (int kt = 0; kt < 4; ++kt)
#pragma unroll
          for (int r = 0; r < 4; ++r) tm = fmaxf(tm, s4[kt][r]);
        tm = fmaxf(tm, __shfl_xor(tm, 16));
        tm = fmaxf(tm, __shfl_xor(tm, 32));
        float mn = fmaxf(m_, tm);
        float al = exp2_fast(m_ - mn);
        m_ = mn;
        float rs = 0.f;
#pragma unroll
        for (int kt = 0; kt < 4; ++kt)
#pragma unroll
          for (int r = 0; r < 4; ++r) {
            float p = exp2_fast(s4[kt][r] - mn);
            s4[kt][r] = p;
            rs += p;
          }
        rs += __shfl_xor(rs, 16);
        rs += __shfl_xor(rs, 32);
        l_ = l_ * al + rs;
#pragma unroll
        for (int dt = 0; dt < 4; ++dt)
#pragma unroll
          for (int r = 0; r < 4; ++r) o[dt][r] *= al;

        // P -> per-wave LDS rows (q = a_, k contiguous), packed bf16 pairs
#pragma unroll
        for (int kt = 0; kt < 4; ++kt) {
          uint2 wp;
          wp.x = pk_bf16(s4[kt][0], s4[kt][1]);
          wp.y = pk_bf16(s4[kt][2], s4[kt][3]);
          *(uint2*)&myP[a_ * 72 + (kt << 4) + (g << 2)] = wp;
        }

        // O^T += V^T P^T : A = Vt rows (d), B = P rows (q); C[d-local][q=a_]
        short8 pf0 = *(const short8*)&myP[a_ * 72 + (g << 3)];
        short8 pf1 = *(const short8*)&myP[a_ * 72 + 32 + (g << 3)];
        __builtin_amdgcn_s_setprio(1);
#pragma unroll
        for (int dt = 0; dt < 4; ++dt) {
          const ushort_t* vr = &Vts[((dt << 4) + a_) * 72];
          short8 va = *(const short8*)&vr[g << 3];
          short8 vb = *(const short8*)&vr[32 + (g << 3)];
          o[dt] = __builtin_amdgcn_mfma_f32_16x16x32_bf16(va, pf0, o[dt], 0, 0, 0);
          o[dt] = __builtin_amdgcn_mfma_f32_16x16x32_bf16(vb, pf1, o[dt], 0, 0, 0);
        }
        __builtin_amdgcn_s_setprio(0);
      }
    }

    // epilogue: lane owns q = a_-row; d = dt*16 + 4g + r contiguous -> float4
    const int b_ = bh >> 4, h = bh & 15;
    const int q = qq0 + (w << 4) + a_;
    float inv = 1.f / l_;
    float* orow = out + ((size_t)(b_ << 11) + q) * 1024 + (h << 6);
#pragma unroll
    for (int dt = 0; dt < 4; ++dt) {
      float4 st;
      st.x = o[dt][0] * inv; st.y = o[dt][1] * inv;
      st.z = o[dt][2] * inv; st.w = o[dt][3] * inv;
      *(float4*)&orow[(dt << 4) + (g << 2)] = st;
    }
  }
}

extern "C" void kernel_launch(void* const* d_in, const int* in_sizes, int n_in,
                              void* d_out, int out_size, void* d_ws, size_t ws_size,
                              hipStream_t stream) {
  const float* x = (const float*)d_in[0];
  const float* W = (const float*)d_in[1];
  const float* b = (const float*)d_in[2];
  float* out = (float*)d_out;

  ushort_t* qkv = (ushort_t*)d_ws;
  ushort_t* xb  = qkv + (size_t)3 * 8388608;
  ushort_t* Wb  = xb + 8388608;

  hipLaunchKernelGGL(cvt_bf16, dim3(4096), dim3(256), 0, stream, x, xb, 8388608);
  hipLaunchKernelGGL(cvt_bf16, dim3(1536), dim3(256), 0, stream, W, Wb, 3145728);
  hipLaunchKernelGGL(qkv_gemm, dim3(1536), dim3(256), 0, stream, xb, Wb, b, qkv);
  hipLaunchKernelGGL(attn_fwd, dim3(512), dim3(512), 0, stream, qkv, out);
}